// Round 11
// baseline (143.500 us; speedup 1.0000x reference)
//
#include <hip/hip_runtime.h>
#include <hip/hip_bf16.h>

// MultiHeadAttention: B=4 H=12 S=2048 D=64 E=768, causal. fp32 in/out, bf16 MFMA compute.
// R10: GEMMs rebuilt BARRIER-FREE: each wave stages its own LDS slice (own 64 A-rows +
//      private B-panel copy), self-paced via own vmcnt (depth-2) + same-wave lgkmcnt.
//      Zero s_barrier in the K-loop. attn unchanged.

typedef __attribute__((ext_vector_type(8))) short bf16x8;
typedef __attribute__((ext_vector_type(4))) float f32x4;
typedef __attribute__((ext_vector_type(16))) float f32x16;
typedef __attribute__((ext_vector_type(4))) uint u32x4;

// ws offsets in bf16 elements
#define OFF_XB   0            // 8192*768            = 6291456
#define OFF_WT   6291456      // 3 * 12*64*768       = 1769472
#define OFF_WPT  8060928      // 768*768             =  589824
#define OFF_QKV  8650752      // q,k: 2 * 6291456; then vt (uints)
#define OFF_AO   27525120     // 8192*768            = 6291456

#define SCALE_LOG2E 0.1803368801111204f   // (1/8) * log2(e)

__device__ inline ushort f2bf(float f) {
  __hip_bfloat16 h = __float2bfloat16(f);
  return *reinterpret_cast<ushort*>(&h);
}
__device__ inline uint cvt_pk(float lo, float hi) {
  uint r;
  asm("v_cvt_pk_bf16_f32 %0, %1, %2" : "=v"(r) : "v"(lo), "v"(hi));
  return r;
}
#define GLOAD16(g, l)                                                              \
  __builtin_amdgcn_global_load_lds(                                                \
      (const __attribute__((address_space(1))) uint*)(g),                          \
      (__attribute__((address_space(3))) uint*)(l), 16, 0, 0)

// per-wave counted wait (no barrier): gate LDS reads on own outstanding gloads
#define WAITN(n)  asm volatile("s_waitcnt vmcnt(" #n ")" ::: "memory")
#define LGKM0()   asm volatile("s_waitcnt lgkmcnt(0)" ::: "memory")

// ---------- fp32 -> bf16 bulk convert (8 elems/thread)
__global__ __launch_bounds__(256) void cvt_bf16(const float* __restrict__ src,
                                                ushort* __restrict__ dst, int n8) {
  int i = blockIdx.x * 256 + threadIdx.x;
  if (i >= n8) return;
  float4 a = *(const float4*)&src[(size_t)i * 8];
  float4 b = *(const float4*)&src[(size_t)i * 8 + 4];
  u32x4 pk = {cvt_pk(a.x, a.y), cvt_pk(a.z, a.w), cvt_pk(b.x, b.y), cvt_pk(b.z, b.w)};
  *(bf16x8*)&dst[(size_t)i * 8] = __builtin_bit_cast(bf16x8, pk);
}

// ---------- tiled 64x64 transpose+convert for the three QKV weights (y = mat 0..35)
__global__ __launch_bounds__(256) void transpose_wqkv(const float* __restrict__ Wq,
                                                      const float* __restrict__ Wk,
                                                      const float* __restrict__ Wv,
                                                      ushort* __restrict__ dst) {
  __shared__ ushort tile[64][130];
  int mat = blockIdx.y;       // 0..35
  int te = blockIdx.x;        // 0..11 (E tiles)
  const float* src = (mat < 12) ? Wq : (mat < 24) ? Wk : Wv;
  int m12 = mat % 12;
  size_t base = (size_t)m12 * 768 * 64;
  int t = threadIdx.x;
#pragma unroll
  for (int i = 0; i < 16; i++) {
    int idx = i * 256 + t;
    int r = idx >> 6, c = idx & 63;
    tile[r][c] = f2bf(src[base + (size_t)(te * 64 + r) * 64 + c]);
  }
  __syncthreads();
  size_t obase = (size_t)mat * 49152;  // 64*768
#pragma unroll
  for (int i = 0; i < 16; i++) {
    int idx = i * 256 + t;
    int c = idx >> 6, r = idx & 63;
    dst[obase + (size_t)c * 768 + te * 64 + r] = tile[r][c];
  }
}

// ---------- tiled 64x64 transpose+convert: fp32 [Edim][Ddim] -> bf16 [Ddim][Edim]
__global__ __launch_bounds__(256) void transpose_w(const float* __restrict__ src,
                                                   ushort* __restrict__ dst,
                                                   int Edim, int Ddim) {
  __shared__ ushort tile[64][130];
  int ntd = Ddim >> 6;
  int te = blockIdx.x / ntd, td = blockIdx.x % ntd;
  int t = threadIdx.x;
#pragma unroll
  for (int i = 0; i < 16; i++) {
    int idx = i * 256 + t;
    int r = idx >> 6, c = idx & 63;
    tile[r][c] = f2bf(src[(size_t)(te * 64 + r) * Ddim + td * 64 + c]);
  }
  __syncthreads();
#pragma unroll
  for (int i = 0; i < 16; i++) {
    int idx = i * 256 + t;
    int c = idx >> 6, r = idx & 63;
    dst[(size_t)(td * 64 + c) * Edim + te * 64 + r] = tile[r][c];
  }
}

// swizzle term for row: ((row + (row>>2)) & 3); row multiples of 16/64 drop out mod 4
__device__ inline uint swz(uint row) { return (row + (row >> 2)) & 3; }

// ---------- QKV GEMM: xb[8192,768] @ Wt(2304x768) -> q,k,vt
// grid (64, 18), 128 thr = 2 waves; wave w owns rows w*64, all 128 cols; BARRIER-FREE:
// per-wave LDS slice (A own rows 4KB + B copy 8KB) x2 buffers; depth-2 vmcnt pipeline.
__global__ __launch_bounds__(128) void gemm_qkv(const ushort* __restrict__ X,
                                                const ushort* __restrict__ Wt,
                                                ushort* __restrict__ qkv,
                                                uint* __restrict__ vtg) {
  __shared__ ushort Aw[2][2][64 * 32];    // [wave][buf]
  __shared__ ushort Bw[2][2][128 * 32];   // [wave][buf]
  int mb = blockIdx.x, nb = blockIdx.y;
  int t = threadIdx.x, w = t >> 6, lane = t & 63, lo = lane & 15, g = lane >> 4;
  const char* Ab = (const char*)(X + ((size_t)mb * 128 + w * 64) * 768);
  const char* Bb = (const char*)(Wt + (size_t)nb * 128 * 768);
  f32x4 acc[4][8];
#pragma unroll
  for (int fi = 0; fi < 4; fi++)
#pragma unroll
    for (int fj = 0; fj < 8; fj++) acc[fi][fj] = (f32x4){0.f, 0.f, 0.f, 0.f};
  // per-lane source byte offsets (swizzled): A 4 chunks, B 8 chunks
  uint aoff[4], boff[8];
#pragma unroll
  for (int j = 0; j < 4; j++) {
    uint ci = j * 64 + lane, row = ci >> 2, c = ci & 3;
    aoff[j] = row * 1536 + (((c ^ swz(row))) << 4);
  }
#pragma unroll
  for (int j = 0; j < 8; j++) {
    uint ci = j * 64 + lane, row = ci >> 2, c = ci & 3;
    boff[j] = row * 1536 + (((c ^ swz(row))) << 4);
  }
  ushort* Awb = &Aw[w][0][0];
  ushort* Bwb = &Bw[w][0][0];

#define QKV_STAGE(tile, buf)                                                        \
  {                                                                                 \
    uint e2 = (uint)(tile) * 64;  /* byte offset of k-slice */                      \
    _Pragma("unroll")                                                               \
    for (int j = 0; j < 4; j++)                                                     \
      GLOAD16(Ab + aoff[j] + e2, Awb + (buf) * 2048 + j * 512);                     \
    _Pragma("unroll")                                                               \
    for (int j = 0; j < 8; j++)                                                     \
      GLOAD16(Bb + boff[j] + e2, Bwb + (buf) * 4096 + j * 512);                     \
  }

  QKV_STAGE(0, 0);
  QKV_STAGE(1, 1);
  uint rsw = swz(lo) << 4;
  for (int it = 0; it < 24; ++it) {
    if (it < 23) { WAITN(12); } else { WAITN(0); }
    const char* Acur = (const char*)(Awb + (it & 1) * 2048);
    const char* Bcur = (const char*)(Bwb + (it & 1) * 4096);
    bf16x8 af[4], bf[8];
#pragma unroll
    for (int fi = 0; fi < 4; fi++) {
      uint arow = fi * 16 + lo;
      af[fi] = *(const bf16x8*)(Acur + arow * 64 + ((g << 4) ^ rsw));
    }
#pragma unroll
    for (int fj = 0; fj < 8; fj++) {
      uint brow = fj * 16 + lo;
      bf[fj] = *(const bf16x8*)(Bcur + brow * 64 + ((g << 4) ^ rsw));
    }
#pragma unroll
    for (int fi = 0; fi < 4; fi++)
#pragma unroll
      for (int fj = 0; fj < 8; fj++)
        acc[fi][fj] = __builtin_amdgcn_mfma_f32_16x16x32_bf16(af[fi], bf[fj], acc[fi][fj], 0, 0, 0);
    if (it < 22) {
      LGKM0();  // my ds_reads of this buffer done before gload writes can land in it
      QKV_STAGE(it + 2, it & 1);
    }
  }
#undef QKV_STAGE
#pragma unroll
  for (int fj = 0; fj < 8; fj++) {
    int mat = nb * 2 + (fj >> 2);  // 0..35
    int ty = mat / 12, h = mat % 12;
    int d = (fj & 3) * 16 + lo;
    if (ty < 2) {
#pragma unroll
      for (int fi = 0; fi < 4; fi++)
#pragma unroll
        for (int rr = 0; rr < 4; rr++) {
          int m = mb * 128 + w * 64 + fi * 16 + g * 4 + rr;
          int b = m >> 11, s = m & 2047;
          qkv[(size_t)ty * 6291456 + (size_t)(b * 12 + h) * 131072 + (size_t)s * 64 + d] =
              f2bf(acc[fi][fj][rr]);
        }
    } else {
      // v: transposed pair-packed per head: [32 tiles][64 d][32 kv-pairs] uints
#pragma unroll
      for (int fi = 0; fi < 4; fi++)
#pragma unroll
        for (int rr = 0; rr < 4; rr += 2) {
          int m = mb * 128 + w * 64 + fi * 16 + g * 4 + rr;
          int b = m >> 11, s = m & 2047;
          uint pk = cvt_pk(acc[fi][fj][rr], acc[fi][fj][rr + 1]);
          vtg[(size_t)(b * 12 + h) * 65536 + (s >> 6) * 2048 + d * 32 + ((s & 63) >> 1)] = pk;
        }
    }
  }
}

// ---------- causal flash attention (unchanged): fixed-max softmax, l via MFMA(ones).
__global__ __launch_bounds__(256, 3) void attn_fwd(const ushort* __restrict__ Qg,
                                                   const ushort* __restrict__ Kg,
                                                   const uint* __restrict__ Vtg,
                                                   ushort* __restrict__ ao) {
  __shared__ ushort Ksh[2][64 * 72];
  __shared__ uint Vsh[2][64 * 36];
  int x = blockIdx.x;
  int head = x % 48;
  int qb = 15 - x / 48;
  int T = 2 * qb + 2;
  int t = threadIdx.x, w = t >> 6, q31 = t & 31, hi = (t & 63) >> 5;
  const ushort* Q = Qg + (size_t)head * 131072;
  const ushort* K = Kg + (size_t)head * 131072;
  const uint* V = Vtg + (size_t)head * 65536;
  int qstart = qb * 128 + 32 * w;
  int qg = qstart + q31;
  bf16x8 qf[4];
#pragma unroll
  for (int s = 0; s < 4; s++)
    qf[s] = *(const bf16x8*)&Q[(size_t)qg * 64 + s * 16 + hi * 8];
  bf16x8 ones;
#pragma unroll
  for (int i = 0; i < 8; i++) ones[i] = (short)0x3F80;
  f32x16 oacc[2], lacc;
#pragma unroll
  for (int r = 0; r < 16; r++) { oacc[0][r] = 0.f; oacc[1][r] = 0.f; lacc[r] = 0.f; }
  int sr = t >> 3, sc = t & 7;
  bf16x8 kreg[2];
  u32x4 vreg[2];
#pragma unroll
  for (int i = 0; i < 2; i++) {
    kreg[i] = *(const bf16x8*)&K[(size_t)(i * 32 + sr) * 64 + sc * 8];
    vreg[i] = *(const u32x4*)&V[(i * 32 + sr) * 32 + sc * 4];
  }
#pragma unroll
  for (int i = 0; i < 2; i++) {
    *(bf16x8*)&Ksh[0][(i * 32 + sr) * 72 + sc * 8] = kreg[i];
    *(u32x4*)&Vsh[0][(i * 32 + sr) * 36 + sc * 4] = vreg[i];
  }
  for (int kb = 0; kb < T; kb++) {
    __syncthreads();
    if (kb + 1 < T) {
      int t1 = (kb + 1) * 64;
#pragma unroll
      for (int i = 0; i < 2; i++) {
        kreg[i] = *(const bf16x8*)&K[(size_t)(t1 + i * 32 + sr) * 64 + sc * 8];
        vreg[i] = *(const u32x4*)&V[(kb + 1) * 2048 + (i * 32 + sr) * 32 + sc * 4];
      }
    }
    int t0 = kb * 64;
    if (t0 <= qstart + 31) {
      const ushort* Kb = Ksh[kb & 1];
      const uint* Vb = Vsh[kb & 1];
      bool act1 = (t0 + 32 <= qstart + 31);
      f32x16 st0, st1;
#pragma unroll
      for (int r = 0; r < 16; r++) { st0[r] = 0.f; st1[r] = 0.f; }
#pragma unroll
      for (int s = 0; s < 4; s++) {
        bf16x8 kf = *(const bf16x8*)&Kb[q31 * 72 + s * 16 + hi * 8];
        st0 = __builtin_amdgcn_mfma_f32_32x32x16_bf16(kf, qf[s], st0, 0, 0, 0);
      }
      if (act1) {
#pragma unroll
        for (int s = 0; s < 4; s++) {
          bf16x8 kf = *(const bf16x8*)&Kb[(32 + q31) * 72 + s * 16 + hi * 8];
          st1 = __builtin_amdgcn_mfma_f32_32x32x16_bf16(kf, qf[s], st1, 0, 0, 0);
        }
      }
      if (t0 + 31 > qstart) {
        int base = t0 - qstart;
#pragma unroll
        for (int r = 0; r < 16; r++) {
          int crow = (r & 3) + 8 * (r >> 2) + 4 * hi;
          if (base + crow > q31) st0[r] = -3e38f;
        }
      }
      if (act1 && (t0 + 63 > qstart)) {
        int base = t0 + 32 - qstart;
#pragma unroll
        for (int r = 0; r < 16; r++) {
          int crow = (r & 3) + 8 * (r >> 2) + 4 * hi;
          if (base + crow > q31) st1[r] = -3e38f;
        }
      }
#pragma unroll
      for (int r = 0; r < 16; r++)
        st0[r] = __builtin_amdgcn_exp2f(st0[r] * SCALE_LOG2E);
      if (act1) {
#pragma unroll
        for (int r = 0; r < 16; r++)
          st1[r] = __builtin_amdgcn_exp2f(st1[r] * SCALE_LOG2E);
      }
      int ns = act1 ? 4 : 2;
      bf16x8 paf[4];
#pragma unroll
      for (int s = 0; s < 4; s++) {
        if (s < ns) {
          const f32x16& sv = (s < 2) ? st0 : st1;
          int rb = (s & 1) * 8;
          uint a = cvt_pk(sv[rb + 0], sv[rb + 1]);
          uint b2 = cvt_pk(sv[rb + 2], sv[rb + 3]);
          uint c = cvt_pk(sv[rb + 4], sv[rb + 5]);
          uint d = cvt_pk(sv[rb + 6], sv[rb + 7]);
          asm volatile("v_permlane32_swap_b32 %0, %1" : "+v"(a), "+v"(c));
          asm volatile("v_permlane32_swap_b32 %0, %1" : "+v"(b2), "+v"(d));
          u32x4 u4 = {a, b2, c, d};
          paf[s] = __builtin_bit_cast(bf16x8, u4);
        }
      }
#pragma unroll
      for (int s = 0; s < 4; s++) {
        if (s < ns) {
          lacc = __builtin_amdgcn_mfma_f32_32x32x16_bf16(paf[s], ones, lacc, 0, 0, 0);
#pragma unroll
          for (int dt = 0; dt < 2; dt++) {
            bf16x8 vf = *(const bf16x8*)&Vb[(dt * 32 + q31) * 36 + s * 8 + hi * 4];
            oacc[dt] = __builtin_amdgcn_mfma_f32_32x32x16_bf16(paf[s], vf, oacc[dt], 0, 0, 0);
          }
        }
      }
    }
    if (kb + 1 < T) {
      int b2 = (kb + 1) & 1;
#pragma unroll
      for (int i = 0; i < 2; i++) {
        *(bf16x8*)&Ksh[b2][(i * 32 + sr) * 72 + sc * 8] = kreg[i];
        *(u32x4*)&Vsh[b2][(i * 32 + sr) * 36 + sc * 4] = vreg[i];
      }
    }
  }
  int hh = head % 12, bb = head / 12;
#pragma unroll
  for (int dt = 0; dt < 2; dt++)
#pragma unroll
    for (int r = 0; r < 16; r++) {
      int qr = qstart + (r & 3) + 8 * (r >> 2) + 4 * hi;
      ao[(size_t)(bb * 2048 + qr) * 768 + hh * 64 + dt * 32 + q31] =
          f2bf(oacc[dt][r] / lacc[r]);
    }
}

// ---------- output projection: ao[8192,768] @ Wpt + bp -> out fp32.
// grid (64, 6), 128 thr = 2 waves; barrier-free per-wave staging, same as gemm_qkv.
__global__ __launch_bounds__(128) void gemm_out(const ushort* __restrict__ A,
                                                const ushort* __restrict__ Bt,
                                                const float* __restrict__ bias,
                                                float* __restrict__ out) {
  __shared__ ushort Aw[2][2][64 * 32];
  __shared__ ushort Bw[2][2][128 * 32];
  int mb = blockIdx.x, nb = blockIdx.y;
  int t = threadIdx.x, w = t >> 6, lane = t & 63, lo = lane & 15, g = lane >> 4;
  const char* Ab = (const char*)(A + ((size_t)mb * 128 + w * 64) * 768);
  const char* Bb = (const char*)(Bt + (size_t)nb * 128 * 768);
  f32x4 acc[4][8];
#pragma unroll
  for (int fi = 0; fi < 4; fi++)
#pragma unroll
    for (int fj = 0; fj < 8; fj++) acc[fi][fj] = (f32x4){0.f, 0.f, 0.f, 0.f};
  uint aoff[4], boff[8];
#pragma unroll
  for (int j = 0; j < 4; j++) {
    uint ci = j * 64 + lane, row = ci >> 2, c = ci & 3;
    aoff[j] = row * 1536 + (((c ^ swz(row))) << 4);
  }
#pragma unroll
  for (int j = 0; j < 8; j++) {
    uint ci = j * 64 + lane, row = ci >> 2, c = ci & 3;
    boff[j] = row * 1536 + (((c ^ swz(row))) << 4);
  }
  ushort* Awb = &Aw[w][0][0];
  ushort* Bwb = &Bw[w][0][0];

#define OUT_STAGE(tile, buf)                                                        \
  {                                                                                 \
    uint e2 = (uint)(tile) * 64;                                                    \
    _Pragma("unroll")                                                               \
    for (int j = 0; j < 4; j++)                                                     \
      GLOAD16(Ab + aoff[j] + e2, Awb + (buf) * 2048 + j * 512);                     \
    _Pragma("unroll")                                                               \
    for (int j = 0; j < 8; j++)                                                     \
      GLOAD16(Bb + boff[j] + e2, Bwb + (buf) * 4096 + j * 512);                     \
  }

  OUT_STAGE(0, 0);
  OUT_STAGE(1, 1);
  uint rsw = swz(lo) << 4;
  for (int it = 0; it < 24; ++it) {
    if (it < 23) { WAITN(12); } else { WAITN(0); }
    const char* Acur = (const char*)(Awb + (it & 1) * 2048);
    const char* Bcur = (const char*)(Bwb + (it & 1) * 4096);
    bf16x8 af[4], bf[8];
#pragma unroll
    for (int fi = 0; fi < 4; fi++) {
      uint arow = fi * 16 + lo;
      af[fi] = *(const bf16x8*)(Acur + arow * 64 + ((g << 4) ^ rsw));
    }
#pragma unroll
    for (int fj = 0; fj < 8; fj++) {
      uint brow = fj * 16 + lo;
      bf[fj] = *(const bf16x8*)(Bcur + brow * 64 + ((g << 4) ^ rsw));
    }
#pragma unroll
    for (int fi = 0; fi < 4; fi++)
#pragma unroll
      for (int fj = 0; fj < 8; fj++)
        acc[fi][fj] = __builtin_amdgcn_mfma_f32_16x16x32_bf16(af[fi], bf[fj], acc[fi][fj], 0, 0, 0);
    if (it < 22) {
      LGKM0();
      OUT_STAGE(it + 2, it & 1);
    }
  }
#undef OUT_STAGE
#pragma unroll
  for (int fj = 0; fj < 8; fj++) {
    int col = nb * 128 + fj * 16 + lo;
    float bv = bias[col];
#pragma unroll
    for (int fi = 0; fi < 4; fi++)
#pragma unroll
      for (int rr = 0; rr < 4; rr++) {
        int m = mb * 128 + w * 64 + fi * 16 + g * 4 + rr;
        out[(size_t)m * 768 + col] = acc[fi][fj][rr] + bv;
      }
  }
}

extern "C" void kernel_launch(void* const* d_in, const int* in_sizes, int n_in,
                              void* d_out, int out_size, void* d_ws, size_t ws_size,
                              hipStream_t stream) {
  const float* x  = (const float*)d_in[0];
  const float* Wq = (const float*)d_in[1];
  const float* Wk = (const float*)d_in[2];
  const float* Wv = (const float*)d_in[3];
  const float* Wp = (const float*)d_in[4];
  const float* bp = (const float*)d_in[5];
  float* out = (float*)d_out;
  ushort* ws = (ushort*)d_ws;

  ushort* xb  = ws + OFF_XB;
  ushort* wt  = ws + OFF_WT;
  ushort* wpt = ws + OFF_WPT;
  ushort* qkv = ws + OFF_QKV;                          // q, k
  uint*   vt  = (uint*)(ws + OFF_QKV + 2 * 6291456);   // packed-transposed v
  ushort* ao  = ws + OFF_AO;

  cvt_bf16<<<dim3(3072), 256, 0, stream>>>(x, xb, 786432);
  transpose_wqkv<<<dim3(12, 36), 256, 0, stream>>>(Wq, Wk, Wv, wt);
  transpose_w<<<dim3(144), 256, 0, stream>>>(Wp, wpt, 768, 768);

  gemm_qkv<<<dim3(64, 18), 128, 0, stream>>>(xb, wt, qkv, vt);
  attn_fwd<<<dim3(768), 256, 0, stream>>>(qkv, qkv + 6291456, vt, ao);
  gemm_out<<<dim3(64, 6), 128, 0, stream>>>(ao, wpt, bp, out);
}

// Round 13
// 137.458 us; speedup vs baseline: 1.0440x; 1.0440x over previous
//
#include <hip/hip_runtime.h>
#include <hip/hip_bf16.h>

// MultiHeadAttention: B=4 H=12 S=2048 D=64 E=768, causal. fp32 in/out, bf16 MFMA compute.
// R12: 8-phase gemm_qkv race FIXED: counted waits fused into the PRECEDING phase-ending
//      barrier (wait-then-barrier-then-read), tail iteration peeled with exact waits
//      (6,1,0). Otherwise identical to R11. gemm_out R8-form, attn R5-form.

typedef __attribute__((ext_vector_type(8))) short bf16x8;
typedef __attribute__((ext_vector_type(4))) float f32x4;
typedef __attribute__((ext_vector_type(16))) float f32x16;
typedef __attribute__((ext_vector_type(4))) uint u32x4;

// ws offsets in bf16 elements
#define OFF_XB   0            // 8192*768            = 6291456
#define OFF_WT   6291456      // 3 * 12*64*768       = 1769472
#define OFF_WPT  8060928      // 768*768             =  589824
#define OFF_QKV  8650752      // q,k: 2 * 6291456; then vt (uints)
#define OFF_AO   27525120     // 8192*768            = 6291456

#define SCALE_LOG2E 0.1803368801111204f   // (1/8) * log2(e)

__device__ inline ushort f2bf(float f) {
  __hip_bfloat16 h = __float2bfloat16(f);
  return *reinterpret_cast<ushort*>(&h);
}
__device__ inline uint cvt_pk(float lo, float hi) {
  uint r;
  asm("v_cvt_pk_bf16_f32 %0, %1, %2" : "=v"(r) : "v"(lo), "v"(hi));
  return r;
}
#define GLOAD16(gp, lp)                                                            \
  __builtin_amdgcn_global_load_lds(                                                \
      (const __attribute__((address_space(1))) uint*)(gp),                         \
      (__attribute__((address_space(3))) uint*)(lp), 16, 0, 0)

#define WAITBAR(n) asm volatile("s_waitcnt vmcnt(" #n ")\ns_barrier" ::: "memory")
#define ENDBAR()   asm volatile("s_waitcnt lgkmcnt(0)\ns_barrier" ::: "memory")
#define LGKM0()    asm volatile("s_waitcnt lgkmcnt(0)" ::: "memory")
#define BAR()      __builtin_amdgcn_s_barrier()
#define SCHED0()   __builtin_amdgcn_sched_barrier(0)

// ---------- fp32 -> bf16 bulk convert (8 elems/thread)
__global__ __launch_bounds__(256) void cvt_bf16(const float* __restrict__ src,
                                                ushort* __restrict__ dst, int n8) {
  int i = blockIdx.x * 256 + threadIdx.x;
  if (i >= n8) return;
  float4 a = *(const float4*)&src[(size_t)i * 8];
  float4 b = *(const float4*)&src[(size_t)i * 8 + 4];
  u32x4 pk = {cvt_pk(a.x, a.y), cvt_pk(a.z, a.w), cvt_pk(b.x, b.y), cvt_pk(b.z, b.w)};
  *(bf16x8*)&dst[(size_t)i * 8] = __builtin_bit_cast(bf16x8, pk);
}

// ---------- tiled 64x64 transpose+convert for the three QKV weights (y = mat 0..35)
__global__ __launch_bounds__(256) void transpose_wqkv(const float* __restrict__ Wq,
                                                      const float* __restrict__ Wk,
                                                      const float* __restrict__ Wv,
                                                      ushort* __restrict__ dst) {
  __shared__ ushort tile[64][130];
  int mat = blockIdx.y;
  int te = blockIdx.x;
  const float* src = (mat < 12) ? Wq : (mat < 24) ? Wk : Wv;
  int m12 = mat % 12;
  size_t base = (size_t)m12 * 768 * 64;
  int t = threadIdx.x;
#pragma unroll
  for (int i = 0; i < 16; i++) {
    int idx = i * 256 + t;
    int r = idx >> 6, c = idx & 63;
    tile[r][c] = f2bf(src[base + (size_t)(te * 64 + r) * 64 + c]);
  }
  __syncthreads();
  size_t obase = (size_t)mat * 49152;
#pragma unroll
  for (int i = 0; i < 16; i++) {
    int idx = i * 256 + t;
    int c = idx >> 6, r = idx & 63;
    dst[obase + (size_t)c * 768 + te * 64 + r] = tile[r][c];
  }
}

// ---------- tiled 64x64 transpose+convert: fp32 [Edim][Ddim] -> bf16 [Ddim][Edim]
__global__ __launch_bounds__(256) void transpose_w(const float* __restrict__ src,
                                                   ushort* __restrict__ dst,
                                                   int Edim, int Ddim) {
  __shared__ ushort tile[64][130];
  int ntd = Ddim >> 6;
  int te = blockIdx.x / ntd, td = blockIdx.x % ntd;
  int t = threadIdx.x;
#pragma unroll
  for (int i = 0; i < 16; i++) {
    int idx = i * 256 + t;
    int r = idx >> 6, c = idx & 63;
    tile[r][c] = f2bf(src[(size_t)(te * 64 + r) * Ddim + td * 64 + c]);
  }
  __syncthreads();
#pragma unroll
  for (int i = 0; i < 16; i++) {
    int idx = i * 256 + t;
    int c = idx >> 6, r = idx & 63;
    dst[(size_t)(td * 64 + c) * Edim + te * 64 + r] = tile[r][c];
  }
}

__device__ inline uint swz(uint row) { return (row + (row >> 2)) & 3; }
__device__ inline uint swz3(uint r) { return (r + (r >> 3)) & 7; }

// ---------- QKV GEMM, 8-phase: xb[8192,768] @ Wt(2304x768) -> q,k,vt
// grid 576 (XCD-chunked), 512 thr = 8 waves (wm=w>>2, wn=w&3). BM=128 BN=256 BK=64.
// A-half h=(row>>5)&1 (interleaved 32-row groups); B-half = 128 cols.
// Sync: every counted wait is fused with the PRECEDING phase-ending barrier
// (wait-then-barrier-then-read). Main loop ends: ph1/ph5 WAITBAR(8), ph3/ph7 WAITBAR(6).
// Last iteration peeled: ph1 WAITBAR(6), ph3 WAITBAR(1), ph5 WAITBAR(0).
__global__ __launch_bounds__(512, 2) void gemm_qkv(const ushort* __restrict__ X,
                                                   const ushort* __restrict__ Wt,
                                                   ushort* __restrict__ qkv,
                                                   uint* __restrict__ vtg) {
  __shared__ ushort Ash[2][2][4096];   // [dbuf][half][64*64]
  __shared__ ushort Bsh[2][2][8192];   // [dbuf][half][128*64]
  int bx = blockIdx.x;
  int wg = (bx & 7) * 72 + (bx >> 3);
  int nb = wg / 64, mb = wg % 64;
  int t = threadIdx.x, w = t >> 6, lane = t & 63, lo = lane & 15, g = lane >> 4;
  int wm = w >> 2, wn = w & 3;
  const char* Ab = (const char*)X + (size_t)mb * 128 * 1536;
  const char* Bb = (const char*)Wt + (size_t)nb * 256 * 1536;
  f32x4 acc[4][4];
#pragma unroll
  for (int fi = 0; fi < 4; fi++)
#pragma unroll
    for (int fj = 0; fj < 4; fj++) acc[fi][fj] = (f32x4){0.f, 0.f, 0.f, 0.f};
  // staging precomputes
  uint arw = (uint)t >> 3, acx = ((uint)t & 7) ^ swz3((uint)t >> 3);
  uint aoff = ((arw & 31) + ((arw >> 5) << 6)) * 1536 + acx * 16;   // + h*49152 + kt*128
  uint brw0 = (uint)t >> 3, brw1 = ((uint)t + 512) >> 3;
  uint boff0 = brw0 * 1536 + ((((uint)t & 7) ^ swz3(brw0)) << 4);   // + h*196608 + kt*128
  uint boff1 = brw1 * 1536 + ((((uint)t & 7) ^ swz3(brw1)) << 4);
  // read precomputes
  uint aro[4], asw[4], bro[4], bsw[4];
#pragma unroll
  for (int fi = 0; fi < 4; fi++) {
    uint r = wm * 64 + fi * 16 + lo;
    uint h = (r >> 5) & 1;
    uint rw = (r & 31) | ((r >> 6) << 5);
    aro[fi] = h * 8192 + rw * 128;
    asw[fi] = swz3(rw);
  }
#pragma unroll
  for (int fj = 0; fj < 4; fj++) {
    uint cc = wn * 64 + fj * 16 + lo;
    uint h = cc >> 7, rw = cc & 127;
    bro[fj] = h * 16384 + rw * 128;
    bsw[fj] = swz3(rw);
  }

#define STAGE_A(kt, h)                                                              \
  GLOAD16(Ab + aoff + (h) * 49152 + (kt) * 128,                                     \
          (char*)Ash + ((kt) & 1) * 16384 + (h) * 8192 + t * 16)
#define STAGE_B(kt, h)                                                              \
  {                                                                                 \
    GLOAD16(Bb + boff0 + (h) * 196608 + (kt) * 128,                                 \
            (char*)Bsh + ((kt) & 1) * 32768 + (h) * 16384 + t * 16);                \
    GLOAD16(Bb + boff1 + (h) * 196608 + (kt) * 128,                                 \
            (char*)Bsh + ((kt) & 1) * 32768 + (h) * 16384 + 8192 + t * 16);         \
  }
#define AREAD(fi, s, db)                                                            \
  (*(const bf16x8*)((const char*)Ash + (db) * 16384 + aro[fi] +                     \
                    ((((s) * 4 + g) ^ asw[fi]) << 4)))
#define BREAD(fj, s, db)                                                            \
  (*(const bf16x8*)((const char*)Bsh + (db) * 32768 + bro[fj] +                     \
                    ((((s) * 4 + g) ^ bsw[fj]) << 4)))
#define MFMA8(fi)                                                                   \
  {                                                                                 \
    __builtin_amdgcn_s_setprio(1);                                                  \
    _Pragma("unroll")                                                               \
    for (int fj = 0; fj < 4; fj++) {                                                \
      acc[fi][fj] = __builtin_amdgcn_mfma_f32_16x16x32_bf16(af0, bfr[fj][0],        \
                                                            acc[fi][fj], 0, 0, 0);  \
      acc[fi][fj] = __builtin_amdgcn_mfma_f32_16x16x32_bf16(af1, bfr[fj][1],        \
                                                            acc[fi][fj], 0, 0, 0);  \
    }                                                                               \
    __builtin_amdgcn_s_setprio(0);                                                  \
  }
#define PHASE_MID() { BAR(); LGKM0(); SCHED0(); }

  // prologue: kt0 {Ah0, Bh0, Bh1, Ah1}, kt1 {Ah0, Bh0, Bh1} = 11 loads
  STAGE_A(0, 0); STAGE_B(0, 0); STAGE_B(0, 1); STAGE_A(0, 1);
  STAGE_A(1, 0); STAGE_B(1, 0); STAGE_B(1, 1);
  WAITBAR(6);   // kt0 Ah0 + B both halves resident (all waves) before ph0 reads

  bf16x8 bfr[4][2];
  bf16x8 af0, af1;
  for (int it = 0; it < 5; ++it) {
    int E = 2 * it, O = 2 * it + 1;
    // ph0: E q0 (+ B-E reads)
    af0 = AREAD(0, 0, 0); af1 = AREAD(0, 1, 0);
#pragma unroll
    for (int fj = 0; fj < 4; fj++) { bfr[fj][0] = BREAD(fj, 0, 0); bfr[fj][1] = BREAD(fj, 1, 0); }
    STAGE_A(O, 1);
    PHASE_MID(); MFMA8(0); BAR();
    // ph1: E q1
    af0 = AREAD(1, 0, 0); af1 = AREAD(1, 1, 0);
    STAGE_B(E + 2, 0);
    PHASE_MID(); MFMA8(1); WAITBAR(8);   // A(E,h1) ready for ph2
    // ph2: E q2
    af0 = AREAD(2, 0, 0); af1 = AREAD(2, 1, 0);
    STAGE_B(E + 2, 1);
    PHASE_MID(); MFMA8(2); BAR();
    // ph3: E q3
    af0 = AREAD(3, 0, 0); af1 = AREAD(3, 1, 0);
    STAGE_A(E + 2, 0);
    PHASE_MID(); MFMA8(3); WAITBAR(6);   // kt O (Ah0 + B both) ready for ph4
    // ph4: O q0 (+ B-O reads)
    af0 = AREAD(0, 0, 1); af1 = AREAD(0, 1, 1);
#pragma unroll
    for (int fj = 0; fj < 4; fj++) { bfr[fj][0] = BREAD(fj, 0, 1); bfr[fj][1] = BREAD(fj, 1, 1); }
    STAGE_A(E + 2, 1);
    PHASE_MID(); MFMA8(0); BAR();
    // ph5: O q1
    af0 = AREAD(1, 0, 1); af1 = AREAD(1, 1, 1);
    STAGE_B(O + 2, 0);
    PHASE_MID(); MFMA8(1); WAITBAR(8);   // A(O,h1) ready for ph6
    // ph6: O q2
    af0 = AREAD(2, 0, 1); af1 = AREAD(2, 1, 1);
    STAGE_B(O + 2, 1);
    PHASE_MID(); MFMA8(2); BAR();
    // ph7: O q3
    af0 = AREAD(3, 0, 1); af1 = AREAD(3, 1, 1);
    STAGE_A(O + 2, 0);
    PHASE_MID(); MFMA8(3); WAITBAR(6);   // kt E+2 ready for next ph0
  }
  // ---- peeled last iteration: E=10, O=11; only A(11,h1) remains to stage
  {
    // ph0
    af0 = AREAD(0, 0, 0); af1 = AREAD(0, 1, 0);
#pragma unroll
    for (int fj = 0; fj < 4; fj++) { bfr[fj][0] = BREAD(fj, 0, 0); bfr[fj][1] = BREAD(fj, 1, 0); }
    STAGE_A(11, 1);
    PHASE_MID(); MFMA8(0); BAR();
    // ph1
    af0 = AREAD(1, 0, 0); af1 = AREAD(1, 1, 0);
    PHASE_MID(); MFMA8(1); WAITBAR(6);   // pops A(10,h1)
    // ph2
    af0 = AREAD(2, 0, 0); af1 = AREAD(2, 1, 0);
    PHASE_MID(); MFMA8(2); BAR();
    // ph3
    af0 = AREAD(3, 0, 0); af1 = AREAD(3, 1, 0);
    PHASE_MID(); MFMA8(3); WAITBAR(1);   // kt11 Ah0 + B both ready
    // ph4
    af0 = AREAD(0, 0, 1); af1 = AREAD(0, 1, 1);
#pragma unroll
    for (int fj = 0; fj < 4; fj++) { bfr[fj][0] = BREAD(fj, 0, 1); bfr[fj][1] = BREAD(fj, 1, 1); }
    PHASE_MID(); MFMA8(0); BAR();
    // ph5
    af0 = AREAD(1, 0, 1); af1 = AREAD(1, 1, 1);
    PHASE_MID(); MFMA8(1); WAITBAR(0);   // A(11,h1) ready
    // ph6
    af0 = AREAD(2, 0, 1); af1 = AREAD(2, 1, 1);
    PHASE_MID(); MFMA8(2); BAR();
    // ph7
    af0 = AREAD(3, 0, 1); af1 = AREAD(3, 1, 1);
    PHASE_MID(); MFMA8(3);
  }
#undef STAGE_A
#undef STAGE_B
#undef AREAD
#undef BREAD
#undef MFMA8
#undef PHASE_MID
  // epilogue: wave tile cols nb*256 + wn*64 -> mat = nb*4 + wn
  int mat = nb * 4 + wn;
  int ty = mat / 12, h = mat % 12;
#pragma unroll
  for (int fj = 0; fj < 4; fj++) {
    int d = fj * 16 + lo;
    if (ty < 2) {
#pragma unroll
      for (int fi = 0; fi < 4; fi++)
#pragma unroll
        for (int rr = 0; rr < 4; rr++) {
          int m = mb * 128 + wm * 64 + fi * 16 + g * 4 + rr;
          int b = m >> 11, s = m & 2047;
          qkv[(size_t)ty * 6291456 + (size_t)(b * 12 + h) * 131072 + (size_t)s * 64 + d] =
              f2bf(acc[fi][fj][rr]);
        }
    } else {
#pragma unroll
      for (int fi = 0; fi < 4; fi++)
#pragma unroll
        for (int rr = 0; rr < 4; rr += 2) {
          int m = mb * 128 + wm * 64 + fi * 16 + g * 4 + rr;
          int b = m >> 11, s = m & 2047;
          uint pk = cvt_pk(acc[fi][fj][rr], acc[fi][fj][rr + 1]);
          vtg[(size_t)(b * 12 + h) * 65536 + (s >> 6) * 2048 + d * 32 + ((s & 63) >> 1)] = pk;
        }
    }
  }
}

// ---------- causal flash attention (unchanged): fixed-max softmax, l via MFMA(ones).
__global__ __launch_bounds__(256, 3) void attn_fwd(const ushort* __restrict__ Qg,
                                                   const ushort* __restrict__ Kg,
                                                   const uint* __restrict__ Vtg,
                                                   ushort* __restrict__ ao) {
  __shared__ ushort Ksh[2][64 * 72];
  __shared__ uint Vsh[2][64 * 36];
  int x = blockIdx.x;
  int head = x % 48;
  int qb = 15 - x / 48;
  int T = 2 * qb + 2;
  int t = threadIdx.x, w = t >> 6, q31 = t & 31, hi = (t & 63) >> 5;
  const ushort* Q = Qg + (size_t)head * 131072;
  const ushort* K = Kg + (size_t)head * 131072;
  const uint* V = Vtg + (size_t)head * 65536;
  int qstart = qb * 128 + 32 * w;
  int qg = qstart + q31;
  bf16x8 qf[4];
#pragma unroll
  for (int s = 0; s < 4; s++)
    qf[s] = *(const bf16x8*)&Q[(size_t)qg * 64 + s * 16 + hi * 8];
  bf16x8 ones;
#pragma unroll
  for (int i = 0; i < 8; i++) ones[i] = (short)0x3F80;
  f32x16 oacc[2], lacc;
#pragma unroll
  for (int r = 0; r < 16; r++) { oacc[0][r] = 0.f; oacc[1][r] = 0.f; lacc[r] = 0.f; }
  int sr = t >> 3, sc = t & 7;
  bf16x8 kreg[2];
  u32x4 vreg[2];
#pragma unroll
  for (int i = 0; i < 2; i++) {
    kreg[i] = *(const bf16x8*)&K[(size_t)(i * 32 + sr) * 64 + sc * 8];
    vreg[i] = *(const u32x4*)&V[(i * 32 + sr) * 32 + sc * 4];
  }
#pragma unroll
  for (int i = 0; i < 2; i++) {
    *(bf16x8*)&Ksh[0][(i * 32 + sr) * 72 + sc * 8] = kreg[i];
    *(u32x4*)&Vsh[0][(i * 32 + sr) * 36 + sc * 4] = vreg[i];
  }
  for (int kb = 0; kb < T; kb++) {
    __syncthreads();
    if (kb + 1 < T) {
      int t1 = (kb + 1) * 64;
#pragma unroll
      for (int i = 0; i < 2; i++) {
        kreg[i] = *(const bf16x8*)&K[(size_t)(t1 + i * 32 + sr) * 64 + sc * 8];
        vreg[i] = *(const u32x4*)&V[(kb + 1) * 2048 + (i * 32 + sr) * 32 + sc * 4];
      }
    }
    int t0 = kb * 64;
    if (t0 <= qstart + 31) {
      const ushort* Kb = Ksh[kb & 1];
      const uint* Vb = Vsh[kb & 1];
      bool act1 = (t0 + 32 <= qstart + 31);
      f32x16 st0, st1;
#pragma unroll
      for (int r = 0; r < 16; r++) { st0[r] = 0.f; st1[r] = 0.f; }
#pragma unroll
      for (int s = 0; s < 4; s++) {
        bf16x8 kf = *(const bf16x8*)&Kb[q31 * 72 + s * 16 + hi * 8];
        st0 = __builtin_amdgcn_mfma_f32_32x32x16_bf16(kf, qf[s], st0, 0, 0, 0);
      }
      if (act1) {
#pragma unroll
        for (int s = 0; s < 4; s++) {
          bf16x8 kf = *(const bf16x8*)&Kb[(32 + q31) * 72 + s * 16 + hi * 8];
          st1 = __builtin_amdgcn_mfma_f32_32x32x16_bf16(kf, qf[s], st1, 0, 0, 0);
        }
      }
      if (t0 + 31 > qstart) {
        int base = t0 - qstart;
#pragma unroll
        for (int r = 0; r < 16; r++) {
          int crow = (r & 3) + 8 * (r >> 2) + 4 * hi;
          if (base + crow > q31) st0[r] = -3e38f;
        }
      }
      if (act1 && (t0 + 63 > qstart)) {
        int base = t0 + 32 - qstart;
#pragma unroll
        for (int r = 0; r < 16; r++) {
          int crow = (r & 3) + 8 * (r >> 2) + 4 * hi;
          if (base + crow > q31) st1[r] = -3e38f;
        }
      }
#pragma unroll
      for (int r = 0; r < 16; r++)
        st0[r] = __builtin_amdgcn_exp2f(st0[r] * SCALE_LOG2E);
      if (act1) {
#pragma unroll
        for (int r = 0; r < 16; r++)
          st1[r] = __builtin_amdgcn_exp2f(st1[r] * SCALE_LOG2E);
      }
      int ns = act1 ? 4 : 2;
      bf16x8 paf[4];
#pragma unroll
      for (int s = 0; s < 4; s++) {
        if (s < ns) {
          const f32x16& sv = (s < 2) ? st0 : st1;
          int rb = (s & 1) * 8;
          uint a = cvt_pk(sv[rb + 0], sv[rb + 1]);
          uint b2 = cvt_pk(sv[rb + 2], sv[rb + 3]);
          uint c = cvt_pk(sv[rb + 4], sv[rb + 5]);
          uint d = cvt_pk(sv[rb + 6], sv[rb + 7]);
          asm volatile("v_permlane32_swap_b32 %0, %1" : "+v"(a), "+v"(c));
          asm volatile("v_permlane32_swap_b32 %0, %1" : "+v"(b2), "+v"(d));
          u32x4 u4 = {a, b2, c, d};
          paf[s] = __builtin_bit_cast(bf16x8, u4);
        }
      }
#pragma unroll
      for (int s = 0; s < 4; s++) {
        if (s < ns) {
          lacc = __builtin_amdgcn_mfma_f32_32x32x16_bf16(paf[s], ones, lacc, 0, 0, 0);
#pragma unroll
          for (int dt = 0; dt < 2; dt++) {
            bf16x8 vf = *(const bf16x8*)&Vb[(dt * 32 + q31) * 36 + s * 8 + hi * 4];
            oacc[dt] = __builtin_amdgcn_mfma_f32_32x32x16_bf16(paf[s], vf, oacc[dt], 0, 0, 0);
          }
        }
      }
    }
    if (kb + 1 < T) {
      int b2 = (kb + 1) & 1;
#pragma unroll
      for (int i = 0; i < 2; i++) {
        *(bf16x8*)&Ksh[b2][(i * 32 + sr) * 72 + sc * 8] = kreg[i];
        *(u32x4*)&Vsh[b2][(i * 32 + sr) * 36 + sc * 4] = vreg[i];
      }
    }
  }
  int hh = head % 12, bb = head / 12;
#pragma unroll
  for (int dt = 0; dt < 2; dt++)
#pragma unroll
    for (int r = 0; r < 16; r++) {
      int qr = qstart + (r & 3) + 8 * (r >> 2) + 4 * hi;
      ao[(size_t)(bb * 2048 + qr) * 768 + hh * 64 + dt * 32 + q31] =
          f2bf(oacc[dt][r] / lacc[r]);
    }
}

// ---------- output projection (R8 form): ao[8192,768] @ Wpt + bp -> out fp32.
// grid (64, 6), 128 thr = 2 waves; depth-2 counted-vmcnt dbuf (wait-then-barrier-then-read).
__global__ __launch_bounds__(128, 2) void gemm_out(const ushort* __restrict__ A,
                                                   const ushort* __restrict__ Bt,
                                                   const float* __restrict__ bias,
                                                   float* __restrict__ out) {
  __shared__ ushort Ash[2][128 * 32];
  __shared__ ushort Bsh[2][128 * 32];
  int mb = blockIdx.x, nb = blockIdx.y;
  int t = threadIdx.x, w = t >> 6, lane = t & 63, lo = lane & 15, g = lane >> 4;
  const ushort* Ab = A + (size_t)mb * 128 * 768;
  const ushort* Bb = Bt + (size_t)nb * 128 * 768;
  f32x4 acc[4][8];
#pragma unroll
  for (int fi = 0; fi < 4; fi++)
#pragma unroll
    for (int fj = 0; fj < 8; fj++) acc[fi][fj] = (f32x4){0.f, 0.f, 0.f, 0.f};
  uint srow[4], ssc[4];
#pragma unroll
  for (int j = 0; j < 4; j++) {
    uint ci = j * 128 + t;
    srow[j] = ci >> 2;
    ssc[j] = ((ci & 3) ^ swz(ci >> 2)) << 4;
  }

#define OUT_STAGE(tile, bsel)                                                         \
  {                                                                                   \
    int e0 = (tile) * 32;                                                             \
    _Pragma("unroll")                                                                 \
    for (int j = 0; j < 4; j++) {                                                     \
      GLOAD16((const char*)(Ab + (size_t)srow[j] * 768 + e0) + ssc[j],                \
              &Ash[bsel][(j * 128 + w * 64) * 8]);                                    \
      GLOAD16((const char*)(Bb + (size_t)srow[j] * 768 + e0) + ssc[j],                \
              &Bsh[bsel][(j * 128 + w * 64) * 8]);                                    \
    }                                                                                 \
  }

  OUT_STAGE(0, 0);
  OUT_STAGE(1, 1);
  uint rsw = swz(lo) << 4;
  for (int it = 0; it < 24; ++it) {
    if (it < 23) { WAITBAR(8); } else { WAITBAR(0); }
    const ushort* Acur = Ash[it & 1];
    const ushort* Bcur = Bsh[it & 1];
    bf16x8 af[4], bf[8];
#pragma unroll
    for (int fi = 0; fi < 4; fi++) {
      int arow = w * 64 + fi * 16 + lo;
      af[fi] = *(const bf16x8*)((const char*)Acur + arow * 64 + ((g << 4) ^ rsw));
    }
#pragma unroll
    for (int fj = 0; fj < 8; fj++) {
      int brow = fj * 16 + lo;
      bf[fj] = *(const bf16x8*)((const char*)Bcur + brow * 64 + ((g << 4) ^ rsw));
    }
#pragma unroll
    for (int fi = 0; fi < 4; fi++)
#pragma unroll
      for (int fj = 0; fj < 8; fj++)
        acc[fi][fj] = __builtin_amdgcn_mfma_f32_16x16x32_bf16(af[fi], bf[fj], acc[fi][fj], 0, 0, 0);
    if (it < 22) {
      ENDBAR();
      OUT_STAGE(it + 2, it & 1);
    }
  }
#undef OUT_STAGE
#pragma unroll
  for (int fj = 0; fj < 8; fj++) {
    int col = nb * 128 + fj * 16 + lo;
    float bv = bias[col];
#pragma unroll
    for (int fi = 0; fi < 4; fi++)
#pragma unroll
      for (int rr = 0; rr < 4; rr++) {
        int m = mb * 128 + w * 64 + fi * 16 + g * 4 + rr;
        out[(size_t)m * 768 + col] = acc[fi][fj][rr] + bv;
      }
  }
}

extern "C" void kernel_launch(void* const* d_in, const int* in_sizes, int n_in,
                              void* d_out, int out_size, void* d_ws, size_t ws_size,
                              hipStream_t stream) {
  const float* x  = (const float*)d_in[0];
  const float* Wq = (const float*)d_in[1];
  const float* Wk = (const float*)d_in[2];
  const float* Wv = (const float*)d_in[3];
  const float* Wp = (const float*)d_in[4];
  const float* bp = (const float*)d_in[5];
  float* out = (float*)d_out;
  ushort* ws = (ushort*)d_ws;

  ushort* xb  = ws + OFF_XB;
  ushort* wt  = ws + OFF_WT;
  ushort* wpt = ws + OFF_WPT;
  ushort* qkv = ws + OFF_QKV;
  uint*   vt  = (uint*)(ws + OFF_QKV + 2 * 6291456);
  ushort* ao  = ws + OFF_AO;

  cvt_bf16<<<dim3(3072), 256, 0, stream>>>(x, xb, 786432);
  transpose_wqkv<<<dim3(12, 36), 256, 0, stream>>>(Wq, Wk, Wv, wt);
  transpose_w<<<dim3(144), 256, 0, stream>>>(Wp, wpt, 768, 768);

  gemm_qkv<<<dim3(576), 512, 0, stream>>>(xb, wt, qkv, vt);
  attn_fwd<<<dim3(768), 256, 0, stream>>>(qkv, qkv + 6291456, vt, ao);
  gemm_out<<<dim3(64, 6), 128, 0, stream>>>(ao, wpt, bp, out);
}